// Round 8
// baseline (199.199 us; speedup 1.0000x reference)
//
#include <hip/hip_runtime.h>
#include <hip/hip_bf16.h>

// Problem constants
#define BB 2
#define SS 2048
#define DD 1024
#define HH 16
#define HDD 64
#define MM (BB*SS)          // 4096
#define NQKV (3*DD)         // 3072
#define SCALE 0.125f        // HD^-0.5
#define QPRESCALE 0.18033688f   // SCALE * log2(e), folded into Q at GEMM epilogue

typedef __bf16 bf16_t;
typedef bf16_t bf16x4 __attribute__((ext_vector_type(4)));
typedef bf16_t bf16x8 __attribute__((ext_vector_type(8)));
typedef float f32x4 __attribute__((ext_vector_type(4)));
typedef float f32x16 __attribute__((ext_vector_type(16)));

// ---------------------------------------------------------------------------
// global -> LDS direct DMA, 16B per lane.
// ---------------------------------------------------------------------------
__device__ __forceinline__ void gl_lds16(const bf16_t* g, bf16_t* l) {
    __builtin_amdgcn_global_load_lds(
        (const __attribute__((address_space(1))) unsigned int*)(uintptr_t)g,
        (__attribute__((address_space(3))) unsigned int*)(uintptr_t)l,
        16, 0, 0);
}

__device__ __forceinline__ f32x4 MF(bf16x8 a, bf16x8 b, f32x4 c) {
    return __builtin_amdgcn_mfma_f32_16x16x32_bf16(a, b, c, 0, 0, 0);
}

// ---------------------------------------------------------------------------
// Fused prep kernel (one launch):
//   blocks [0,2048): convert x f32 -> bf16 (8 elems/thread)
//   blocks [2048,5120): transpose Wqkv -> wqkvt [3072][1024] bf16 (96x32 tiles)
//   blocks [5120,6144): transpose Wproj -> wprojt [1024][1024] bf16 (32x32 tiles)
// ---------------------------------------------------------------------------
__global__ __launch_bounds__(256) void prep(
    const float* __restrict__ x, const float* __restrict__ Wqkv,
    const float* __restrict__ Wproj, bf16_t* __restrict__ xb,
    bf16_t* __restrict__ wqkvt, bf16_t* __restrict__ wprojt)
{
    const int bx = blockIdx.x;
    if (bx < 2048) {
        int i = (bx * 256 + threadIdx.x) * 8;
        float4 a = *(const float4*)(x + i);
        float4 b = *(const float4*)(x + i + 4);
        bf16x8 v;
        v[0]=(bf16_t)a.x; v[1]=(bf16_t)a.y; v[2]=(bf16_t)a.z; v[3]=(bf16_t)a.w;
        v[4]=(bf16_t)b.x; v[5]=(bf16_t)b.y; v[6]=(bf16_t)b.z; v[7]=(bf16_t)b.w;
        *reinterpret_cast<bf16x8*>(xb + i) = v;
        return;
    }
    __shared__ float tile[32][33];
    const float* src; bf16_t* dst; int C, bxl, byl;
    if (bx < 5120) {
        int t = bx - 2048;
        byl = t / 96; bxl = t - byl * 96;   // 96 not pow2 -> real division
        src = Wqkv;  dst = wqkvt;  C = NQKV;
    } else {
        int t = bx - 5120;
        byl = t >> 5; bxl = t & 31;
        src = Wproj; dst = wprojt; C = DD;
    }
    const int R = DD;
    const int tx = threadIdx.x & 31, ty = threadIdx.x >> 5;
    const int r0 = byl * 32, c0 = bxl * 32;
    #pragma unroll
    for (int i = 0; i < 32; i += 8)
        tile[ty + i][tx] = src[(size_t)(r0 + ty + i) * C + c0 + tx];
    __syncthreads();
    #pragma unroll
    for (int i = 0; i < 32; i += 8)
        dst[(size_t)(c0 + ty + i) * R + r0 + tx] = (bf16_t)tile[tx][ty + i];
}

// ---------------------------------------------------------------------------
// QKV GEMM (unchanged from R7, verified): BM=128, BN=128, BK=32, 8 waves,
// 768 blocks = 3/CU, XCD-partitioned, counted-vmcnt 3-buffer pipeline.
// ---------------------------------------------------------------------------
__global__ __launch_bounds__(512, 6) void gemm_qkv(
    const bf16_t* __restrict__ A, const bf16_t* __restrict__ Bt,
    const float* __restrict__ bias,
    bf16_t* __restrict__ qw, bf16_t* __restrict__ kw, bf16_t* __restrict__ vtw)
{
    constexpr int K  = DD;          // 1024
    constexpr int BM = 128, BN = 128, BK = 32;
    constexpr int NT = K / BK;      // 32

    __shared__ __align__(16) bf16_t smem[24576];   // 49152 B -> 3 blocks/CU
    bf16_t* const Ab[3] = { smem,         smem + 4096,  smem + 8192 };
    bf16_t* const Bb[3] = { smem + 12288, smem + 16384, smem + 20480 };

    const int tid  = threadIdx.x;
    const int w    = tid >> 6;
    const int lane = tid & 63;
    const int lr   = lane & 15;
    const int quad = lane >> 4;
    const int wm   = w >> 2;        // 0..1 -> rows wm*64..+63
    const int wn   = w & 3;         // 0..3 -> cols wn*32..+31

    // XCD partition: xcd = flat&7; within XCD an 8(m) x 12(n) sub-grid.
    const int flat = blockIdx.y * 24 + blockIdx.x;
    const int xcd  = flat & 7;
    const int idx  = flat >> 3;            // 0..95
    const int m0   = ((xcd >> 1) * 8 + (idx & 7)) * BM;
    const int n0   = ((xcd & 1) * 12 + (idx >> 3)) * BN;

    f32x4 acc[4][2];
    #pragma unroll
    for (int mi = 0; mi < 4; mi++)
        #pragma unroll
        for (int ni = 0; ni < 2; ni++)
            acc[mi][ni] = (f32x4){0.f, 0.f, 0.f, 0.f};

    const bf16_t* aG = A  + (size_t)(m0 + (tid >> 2)) * K + (tid & 3) * 8;
    const bf16_t* bG = Bt + (size_t)(n0 + (tid >> 2)) * K + (tid & 3) * 8;

    auto stage = [&](int kt, bf16_t* Ad, bf16_t* Bd) {
        const int ko = kt * BK;
        gl_lds16(aG + ko, Ad + tid * 8);
        gl_lds16(bG + ko, Bd + tid * 8);
    };

    stage(0, Ab[0], Bb[0]);
    stage(1, Ab[1], Bb[1]);
    asm volatile("s_waitcnt vmcnt(2)" ::: "memory");
    __builtin_amdgcn_s_barrier();
    __builtin_amdgcn_sched_barrier(0);

    const int aOff = (wm * 64 + lr) * BK + quad * 8;
    const int bOff = (wn * 32 + lr) * BK + quad * 8;

    auto tileStep = [&](int t, const bf16_t* Ac, const bf16_t* Bc,
                        bf16_t* An, bf16_t* Bn) {
        bf16x8 af[4], bk[2];
        #pragma unroll
        for (int mi = 0; mi < 4; mi++)
            af[mi] = *(const bf16x8*)(Ac + aOff + mi * 16 * BK);
        #pragma unroll
        for (int ni = 0; ni < 2; ni++)
            bk[ni] = *(const bf16x8*)(Bc + bOff + ni * 16 * BK);
        if (t < NT - 2) stage(t + 2, An, Bn);
        __builtin_amdgcn_sched_barrier(0);
        __builtin_amdgcn_s_setprio(1);
        #pragma unroll
        for (int mi = 0; mi < 4; mi++)
            #pragma unroll
            for (int ni = 0; ni < 2; ni++)
                acc[mi][ni] = MF(af[mi], bk[ni], acc[mi][ni]);
        __builtin_amdgcn_s_setprio(0);
        __builtin_amdgcn_sched_barrier(0);
        if (t < NT - 2)       asm volatile("s_waitcnt vmcnt(2)" ::: "memory");
        else if (t == NT - 2) asm volatile("s_waitcnt vmcnt(0)" ::: "memory");
        __builtin_amdgcn_s_barrier();
        __builtin_amdgcn_sched_barrier(0);
    };

    #pragma unroll 1
    for (int tt = 0; tt < NT - 2; tt += 3) {
        tileStep(tt,     Ab[0], Bb[0], Ab[2], Bb[2]);
        tileStep(tt + 1, Ab[1], Bb[1], Ab[0], Bb[0]);
        tileStep(tt + 2, Ab[2], Bb[2], Ab[1], Bb[1]);
    }
    tileStep(NT - 2, Ab[0], Bb[0], nullptr, nullptr);   // t=30: vmcnt(0)
    tileStep(NT - 1, Ab[1], Bb[1], nullptr, nullptr);   // t=31

    // ---- epilogue (block-uniform q/k/v branch: BN=128 divides the 1024s) --
    const int which = n0 >> 10;           // 0=q, 1=k, 2=v
    const int dbase = n0 & 1023;
    const int b     = m0 >> 11;
    const int s0    = m0 & 2047;

    if (which < 2) {
        bf16_t* dst = (which == 0) ? qw : kw;
        const float scale = (which == 0) ? QPRESCALE : 1.0f;
        #pragma unroll
        for (int mi = 0; mi < 4; mi++) {
            const int rl0 = wm * 64 + mi * 16 + quad * 4;
            #pragma unroll
            for (int ni = 0; ni < 2; ni++) {
                const int col = n0 + wn * 32 + ni * 16 + lr;
                const float bcol = bias[col];
                const int d = col & 1023;
                const int h = d >> 6, hd = d & 63;
                #pragma unroll
                for (int reg = 0; reg < 4; reg++) {
                    const int s = s0 + rl0 + reg;
                    dst[(((size_t)(b * HH + h)) * SS + s) * HDD + hd] =
                        (bf16_t)((acc[mi][ni][reg] + bcol) * scale);
                }
            }
        }
    } else {
        // all-V block: transpose through LDS, then 16B stores along S
        __builtin_amdgcn_s_barrier();   // LDS reads of last tile done
        #pragma unroll
        for (int mi = 0; mi < 4; mi++) {
            const int rl0 = wm * 64 + mi * 16 + quad * 4;
            #pragma unroll
            for (int ni = 0; ni < 2; ni++) {
                const int lc = wn * 32 + ni * 16 + lr;
                const float bcol = bias[n0 + lc];
                bf16x4 pk;
                #pragma unroll
                for (int reg = 0; reg < 4; reg++)
                    pk[reg] = (bf16_t)(acc[mi][ni][reg] + bcol);
                *reinterpret_cast<bf16x4*>(&smem[lc * 132 + rl0]) = pk;
            }
        }
        __builtin_amdgcn_s_barrier();
        const int lcb = tid >> 4;            // 0..31
        const int rl  = (tid & 15) * 8;      // 0..120
        const int s   = s0 + rl;
        #pragma unroll
        for (int j = 0; j < 4; j++) {
            const int lc = j * 32 + lcb;
            bf16x8 vv = *reinterpret_cast<const bf16x8*>(&smem[lc * 132 + rl]);
            const int d = dbase + lc;
            const int h = d >> 6, hd = d & 63;
            *reinterpret_cast<bf16x8*>(
                vtw + (((size_t)(b * HH + h)) * HDD + hd) * SS + s) = vv;
        }
    }
}

// ---------------------------------------------------------------------------
// Proj GEMM (unchanged from R6/R7): BM=128, BN=128, BK=32, 8 waves,
// 256 blocks, counted-vmcnt 3-buffer pipeline.
// ---------------------------------------------------------------------------
__global__ __launch_bounds__(512, 6) void gemm_proj(
    const bf16_t* __restrict__ A, const bf16_t* __restrict__ Bt,
    const float* __restrict__ bias, float* __restrict__ outf)
{
    constexpr int K  = DD;          // 1024
    constexpr int N  = DD;
    constexpr int BM = 128, BN = 128, BK = 32;
    constexpr int NT = K / BK;      // 32

    __shared__ __align__(16) bf16_t smem[24576];   // 49152 B -> 3 blocks/CU
    bf16_t* const Ab[3] = { smem, smem + 4096, smem + 8192 };
    bf16_t* const Bb[3] = { smem + 12288, smem + 16384, smem + 20480 };

    const int tid  = threadIdx.x;
    const int w    = tid >> 6;
    const int lane = tid & 63;
    const int lr   = lane & 15;
    const int quad = lane >> 4;
    const int wm   = w >> 2;        // 0..1 -> rows wm*64..+63
    const int wn   = w & 3;         // 0..3 -> cols wn*32..+31

    const int flat = blockIdx.y * 8 + blockIdx.x;
    const int swz  = (flat & 7) * 32 + (flat >> 3);
    const int m0   = (swz >> 3) * BM;
    const int n0   = (swz & 7) * BN;

    f32x4 acc[4][2];
    #pragma unroll
    for (int mi = 0; mi < 4; mi++)
        #pragma unroll
        for (int ni = 0; ni < 2; ni++)
            acc[mi][ni] = (f32x4){0.f, 0.f, 0.f, 0.f};

    const bf16_t* aG = A  + (size_t)(m0 + (tid >> 2)) * K + (tid & 3) * 8;
    const bf16_t* bG = Bt + (size_t)(n0 + (tid >> 2)) * K + (tid & 3) * 8;

    auto stage = [&](int kt, bf16_t* Ad, bf16_t* Bd) {
        const int ko = kt * BK;
        gl_lds16(aG + ko, Ad + tid * 8);
        gl_lds16(bG + ko, Bd + tid * 8);
    };

    stage(0, Ab[0], Bb[0]);
    stage(1, Ab[1], Bb[1]);
    asm volatile("s_waitcnt vmcnt(2)" ::: "memory");
    __builtin_amdgcn_s_barrier();
    __builtin_amdgcn_sched_barrier(0);

    const int aOff = (wm * 64 + lr) * BK + quad * 8;
    const int bOff = (wn * 32 + lr) * BK + quad * 8;

    auto tileStep = [&](int t, const bf16_t* Ac, const bf16_t* Bc,
                        bf16_t* An, bf16_t* Bn) {
        bf16x8 af[4], bk[2];
        #pragma unroll
        for (int mi = 0; mi < 4; mi++)
            af[mi] = *(const bf16x8*)(Ac + aOff + mi * 16 * BK);
        #pragma unroll
        for (int ni = 0; ni < 2; ni++)
            bk[ni] = *(const bf16x8*)(Bc + bOff + ni * 16 * BK);
        if (t < NT - 2) stage(t + 2, An, Bn);
        __builtin_amdgcn_sched_barrier(0);
        __builtin_amdgcn_s_setprio(1);
        #pragma unroll
        for (int mi = 0; mi < 4; mi++)
            #pragma unroll
            for (int ni = 0; ni < 2; ni++)
                acc[mi][ni] = MF(af[mi], bk[ni], acc[mi][ni]);
        __builtin_amdgcn_s_setprio(0);
        __builtin_amdgcn_sched_barrier(0);
        if (t < NT - 2)       asm volatile("s_waitcnt vmcnt(2)" ::: "memory");
        else if (t == NT - 2) asm volatile("s_waitcnt vmcnt(0)" ::: "memory");
        __builtin_amdgcn_s_barrier();
        __builtin_amdgcn_sched_barrier(0);
    };

    #pragma unroll 1
    for (int tt = 0; tt < NT - 2; tt += 3) {
        tileStep(tt,     Ab[0], Bb[0], Ab[2], Bb[2]);
        tileStep(tt + 1, Ab[1], Bb[1], Ab[0], Bb[0]);
        tileStep(tt + 2, Ab[2], Bb[2], Ab[1], Bb[1]);
    }
    tileStep(NT - 2, Ab[0], Bb[0], nullptr, nullptr);   // t=30: vmcnt(0)
    tileStep(NT - 1, Ab[1], Bb[1], nullptr, nullptr);   // t=31

    #pragma unroll
    for (int mi = 0; mi < 4; mi++)
        #pragma unroll
        for (int ni = 0; ni < 2; ni++) {
            const int col = n0 + wn * 32 + ni * 16 + lr;
            const float bcol = bias[col];
            #pragma unroll
            for (int reg = 0; reg < 4; reg++) {
                const int row = m0 + wm * 64 + mi * 16 + quad * 4 + reg;
                outf[(size_t)row * N + col] = acc[mi][ni][reg] + bcol;
            }
        }
}

// ---------------------------------------------------------------------------
// Flash attention v10 (R8):
//   - l accumulation via f32x4 partials (break the 32-deep dependent f32
//     add chain per iter -> depth 8, ILP 4; merged once after the loop).
//   - exp/pack halves interleaved with PV halves: exp(ni=0) -> PV(c16=0,1)
//     -> exp(ni=1) -> PV(c16=2,3); the second exp's VALU overlaps the first
//     PV MFMA cluster within the wave.
//   Everything else (XCD bh-pinning, permuted V LDS one-b128 reads,
//   setprio, hoisted prefetch, dbuf, one barrier/iter) unchanged from R7.
// ---------------------------------------------------------------------------
__global__ __launch_bounds__(512, 4) void attn_kernel(
    const bf16_t* __restrict__ qws, const bf16_t* __restrict__ kws,
    const bf16_t* __restrict__ vtws, bf16_t* __restrict__ ob)
{
    __shared__ __align__(16) bf16_t smem[35072];   // 70144 B -> 2 blocks/CU
    bf16_t* Ks = smem;                 // 2 buf x 2 g x 520*8 = 16640 el
    bf16_t* Vs = smem + 16640;         // 2 buf x 2 g x 64*72 = 18432 el

    const int tid  = threadIdx.x;
    const int w    = tid >> 6;
    const int g    = w >> 2;
    const int wg   = w & 3;
    const int lane = tid & 63;
    const int ln31 = lane & 31;
    const int ln5  = lane >> 5;

    // XCD swizzle: all 16 q-blocks of a bh pinned to XCD bh&7.
    const int flat = blockIdx.y * 16 + blockIdx.x;
    const int t2 = flat >> 3;
    const int bh = (t2 >> 4) * 8 + (flat & 7);
    const int qb = t2 & 15;
    const int b  = bh >> 4;
    const int h  = bh & 15;

    const bf16_t* Qh  = qws  + (size_t)bh * SS * HDD;
    const bf16_t* Kh  = kws  + (size_t)bh * SS * HDD;
    const bf16_t* Vth = vtws + (size_t)bh * HDD * SS;

    const int q0w    = qb * 128 + wg * 32;
    const int kvbase = g * 1024;

    bf16x8 aq[4];
    #pragma unroll
    for (int f = 0; f < 4; f++)
        aq[f] = *(const bf16x8*)(Qh + (size_t)(q0w + ln31) * HDD + f * 16 + ln5 * 8);

    const int gtid = tid & 255;
    const int sc = gtid & 7;
    const int sr = gtid >> 3;
    const int vcol = (sc >> 1) * 16 + (sc & 1) * 4;

    {
        const int ko = g * 520;
        const int vo = g * 4608;
        bf16x8 k0 = *(const bf16x8*)(Kh  + (size_t)(kvbase + sr     ) * HDD + sc * 8);
        bf16x8 k1 = *(const bf16x8*)(Kh  + (size_t)(kvbase + sr + 32) * HDD + sc * 8);
        bf16x8 v0 = *(const bf16x8*)(Vth + (size_t)(sr     ) * SS + kvbase + sc * 8);
        bf16x8 v1 = *(const bf16x8*)(Vth + (size_t)(sr + 32) * SS + kvbase + sc * 8);
        *reinterpret_cast<bf16x8*>(&Ks[(ko + sc * 65 + sr     ) * 8]) = k0;
        *reinterpret_cast<bf16x8*>(&Ks[(ko + sc * 65 + sr + 32) * 8]) = k1;
        bf16_t* vd0 = &Vs[vo + (sr     ) * 72 + vcol];
        bf16_t* vd1 = &Vs[vo + (sr + 32) * 72 + vcol];
        *reinterpret_cast<bf16x4*>(vd0)     = __builtin_shufflevector(v0, v0, 0,1,2,3);
        *reinterpret_cast<bf16x4*>(vd0 + 8) = __builtin_shufflevector(v0, v0, 4,5,6,7);
        *reinterpret_cast<bf16x4*>(vd1)     = __builtin_shufflevector(v1, v1, 0,1,2,3);
        *reinterpret_cast<bf16x4*>(vd1 + 8) = __builtin_shufflevector(v1, v1, 4,5,6,7);
    }
    __syncthreads();

    f32x4 lac = (f32x4){0.f, 0.f, 0.f, 0.f};
    f32x16 o[2];
    #pragma unroll
    for (int nh = 0; nh < 2; nh++)
        #pragma unroll
        for (int r = 0; r < 16; r++) o[nh][r] = 0.f;

    int buf = 0;
    for (int it = 0; it < 16; ++it) {
        const int ko = buf * 1040 + g * 520;
        const int vo = buf * 9216 + g * 4608;

        // K/V prefetch for it+1 issued FIRST (independent; long cover)
        bf16x8 nk0, nk1, nv0, nv1;
        const bool more = (it + 1 < 16);
        if (more) {
            const int kvn = kvbase + (it + 1) * 64;
            nk0 = *(const bf16x8*)(Kh  + (size_t)(kvn + sr     ) * HDD + sc * 8);
            nk1 = *(const bf16x8*)(Kh  + (size_t)(kvn + sr + 32) * HDD + sc * 8);
            nv0 = *(const bf16x8*)(Vth + (size_t)(sr     ) * SS + kvn + sc * 8);
            nv1 = *(const bf16x8*)(Vth + (size_t)(sr + 32) * SS + kvn + sc * 8);
        }

        f32x16 sfr[2];
        __builtin_amdgcn_s_setprio(1);
        #pragma unroll
        for (int ni = 0; ni < 2; ni++) {
            #pragma unroll
            for (int r = 0; r < 16; r++) sfr[ni][r] = 0.f;
            #pragma unroll
            for (int f = 0; f < 4; f++) {
                bf16x8 kb = *reinterpret_cast<const bf16x8*>(
                    &Ks[(ko + (2 * f + ln5) * 65 + ni * 32 + ln31) * 8]);
                sfr[ni] = __builtin_amdgcn_mfma_f32_32x32x16_bf16(kb, aq[f], sfr[ni], 0, 0, 0);
            }
        }
        __builtin_amdgcn_s_setprio(0);

        const bf16_t* vrow0 = &Vs[vo + (ln31     ) * 72];
        const bf16_t* vrow1 = &Vs[vo + (32 + ln31) * 72];

        // ---- half 0: exp(ni=0) + pack ap0/ap1 + PV(c16=0,1)
        float p0[16];
        #pragma unroll
        for (int r = 0; r < 16; r++) {
            p0[r] = __builtin_amdgcn_exp2f(sfr[0][r]);
            lac[r & 3] += p0[r];
        }
        bf16x8 ap01[2];
        #pragma unroll
        for (int c16 = 0; c16 < 2; c16++)
            #pragma unroll
            for (int j = 0; j < 8; j++)
                ap01[c16][j] = (bf16_t)p0[c16 * 8 + j];

        __builtin_amdgcn_s_setprio(1);
        #pragma unroll
        for (int c16 = 0; c16 < 2; c16++) {
            bf16x8 vb0 = *reinterpret_cast<const bf16x8*>(vrow0 + c16 * 16 + 8 * ln5);
            bf16x8 vb1 = *reinterpret_cast<const bf16x8*>(vrow1 + c16 * 16 + 8 * ln5);
            o[0] = __builtin_amdgcn_mfma_f32_32x32x16_bf16(ap01[c16], vb0, o[0], 0, 0, 0);
            o[1] = __builtin_amdgcn_mfma_f32_32x32x16_bf16(ap01[c16], vb1, o[1], 0, 0, 0);
        }
        __builtin_amdgcn_s_setprio(0);

        // ---- half 1: exp(ni=1) + pack ap2/ap3 + PV(c16=2,3)
        float p1[16];
        #pragma unroll
        for (int r = 0; r < 16; r++) {
            p1[r] = __builtin_amdgcn_exp2f(sfr[1][r]);
            lac[r & 3] += p1[r];
        }
        bf16x8 ap23[2];
        #pragma unroll
        for (int c16 = 0; c16 < 2; c16++)
            #pragma unroll
            for (int j = 0; j < 8; j++)
                ap23[c16][j] = (bf16_t)p1[c16 * 8 + j];

        __builtin_amdgcn_s_setprio(1);
        #pragma unroll
        for (int c16 = 0; c16 < 2; c16++) {
            bf16x8 vb0 = *reinterpret_cast<const bf16x8*>(vrow0 + (2 + c16) * 16 + 8 * ln5);
            bf16x8 vb1 = *reinterpret_cast<const bf16x8*>(vrow1 + (2 + c16) * 16 + 8 * ln5);
            o[0] = __builtin_amdgcn_mfma_f32_32x32x16_bf16(ap23[c16], vb0, o[0], 0, 0, 0);
            o[1] = __builtin_amdgcn_mfma_f32_32x32x16_bf16(ap23[c16], vb1, o[1], 0, 0, 0);
        }
        __builtin_amdgcn_s_setprio(0);

        if (more) {
            const int ko1 = (buf ^ 1) * 1040 + g * 520;
            const int vo1 = (buf ^ 1) * 9216 + g * 4608;
            *reinterpret_cast<bf16x8*>(&Ks[(ko1 + sc * 65 + sr     ) * 8]) = nk0;
            *reinterpret_cast<bf16x8*>(&Ks[(ko1 + sc * 65 + sr + 32) * 8]) = nk1;
            bf16_t* vd0 = &Vs[vo1 + (sr     ) * 72 + vcol];
            bf16_t* vd1 = &Vs[vo1 + (sr + 32) * 72 + vcol];
            *reinterpret_cast<bf16x4*>(vd0)     = __builtin_shufflevector(nv0, nv0, 0,1,2,3);
            *reinterpret_cast<bf16x4*>(vd0 + 8) = __builtin_shufflevector(nv0, nv0, 4,5,6,7);
            *reinterpret_cast<bf16x4*>(vd1)     = __builtin_shufflevector(nv1, nv1, 0,1,2,3);
            *reinterpret_cast<bf16x4*>(vd1 + 8) = __builtin_shufflevector(nv1, nv1, 4,5,6,7);
        }
        __syncthreads();
        buf ^= 1;
    }

    float l = (lac[0] + lac[1]) + (lac[2] + lac[3]);
    l += __shfl_xor(l, 32, 64);

    __syncthreads();
    float* Of = (float*)smem;
    float* Lf = (float*)(smem + 16384);
    if (ln5 == 0) Lf[g * 128 + wg * 32 + ln31] = l;
    if (g == 1) {
        #pragma unroll
        for (int nh = 0; nh < 2; nh++)
            #pragma unroll
            for (int r = 0; r < 16; r++) {
                const int q = (r & 3) + 8 * (r >> 2) + 4 * ln5;
                Of[(wg * 32 + q) * 64 + nh * 32 + ln31] = o[nh][r];
            }
    }
    __syncthreads();
    if (g == 0) {
        float inv[16];
        #pragma unroll
        for (int r = 0; r < 16; r++) {
            const int q = (r & 3) + 8 * (r >> 2) + 4 * ln5;
            inv[r] = 1.f / (Lf[wg * 32 + q] + Lf[128 + wg * 32 + q]);
        }
        #pragma unroll
        for (int nh = 0; nh < 2; nh++)
            #pragma unroll
            for (int r = 0; r < 16; r++) {
                const int q  = (r & 3) + 8 * (r >> 2) + 4 * ln5;
                const int hd = nh * 32 + ln31;
                float val = (o[nh][r] + Of[(wg * 32 + q) * 64 + hd]) * inv[r];
                ob[((size_t)b * SS + q0w + q) * DD + h * HDD + hd] = (bf16_t)val;
            }
    }
}

// ---------------------------------------------------------------------------
extern "C" void kernel_launch(void* const* d_in, const int* in_sizes, int n_in,
                              void* d_out, int out_size, void* d_ws, size_t ws_size,
                              hipStream_t stream) {
    const float* x     = (const float*)d_in[0];
    const float* Wqkv  = (const float*)d_in[1];
    const float* bqkv  = (const float*)d_in[2];
    const float* Wproj = (const float*)d_in[3];
    const float* bproj = (const float*)d_in[4];
    float* out = (float*)d_out;

    const size_t NEL = (size_t)MM * DD;   // 4194304
    bf16_t* qws    = (bf16_t*)d_ws;
    bf16_t* kws    = qws  + NEL;
    bf16_t* vtws   = kws  + NEL;
    bf16_t* xb     = vtws + NEL;          // aliased: xb then ows
    bf16_t* ows    = xb;
    bf16_t* wqkvt  = xb + NEL;
    bf16_t* wprojt = wqkvt + (size_t)NQKV * DD;

    prep<<<6144, 256, 0, stream>>>(x, Wqkv, Wproj, xb, wqkvt, wprojt);

    gemm_qkv<<<dim3(NQKV / 128, MM / 128), 512, 0, stream>>>(
        xb, wqkvt, bqkv, qws, kws, vtws);

    attn_kernel<<<dim3(SS / 128, BB * HH), 512, 0, stream>>>(qws, kws, vtws, ows);

    gemm_proj<<<dim3(DD / 128, MM / 128), 512, 0, stream>>>(
        ows, wprojt, bproj, out);
}

// Round 9
// 171.319 us; speedup vs baseline: 1.1627x; 1.1627x over previous
//
#include <hip/hip_runtime.h>
#include <hip/hip_bf16.h>

// Problem constants
#define BB 2
#define SS 2048
#define DD 1024
#define HH 16
#define HDD 64
#define MM (BB*SS)          // 4096
#define NQKV (3*DD)         // 3072
#define SCALE 0.125f        // HD^-0.5
#define QPRESCALE 0.18033688f   // SCALE * log2(e), folded into Q at GEMM epilogue

typedef __bf16 bf16_t;
typedef bf16_t bf16x4 __attribute__((ext_vector_type(4)));
typedef bf16_t bf16x8 __attribute__((ext_vector_type(8)));
typedef float f32x4 __attribute__((ext_vector_type(4)));
typedef float f32x16 __attribute__((ext_vector_type(16)));

// ---------------------------------------------------------------------------
// global -> LDS direct DMA, 16B per lane.
// ---------------------------------------------------------------------------
__device__ __forceinline__ void gl_lds16(const bf16_t* g, bf16_t* l) {
    __builtin_amdgcn_global_load_lds(
        (const __attribute__((address_space(1))) unsigned int*)(uintptr_t)g,
        (__attribute__((address_space(3))) unsigned int*)(uintptr_t)l,
        16, 0, 0);
}

__device__ __forceinline__ f32x4 MF(bf16x8 a, bf16x8 b, f32x4 c) {
    return __builtin_amdgcn_mfma_f32_16x16x32_bf16(a, b, c, 0, 0, 0);
}

// ---------------------------------------------------------------------------
// Fused prep kernel (one launch):
//   blocks [0,2048): convert x f32 -> bf16 (8 elems/thread)
//   blocks [2048,5120): transpose Wqkv -> wqkvt [3072][1024] bf16 (96x32 tiles)
//   blocks [5120,6144): transpose Wproj -> wprojt [1024][1024] bf16 (32x32 tiles)
// ---------------------------------------------------------------------------
__global__ __launch_bounds__(256) void prep(
    const float* __restrict__ x, const float* __restrict__ Wqkv,
    const float* __restrict__ Wproj, bf16_t* __restrict__ xb,
    bf16_t* __restrict__ wqkvt, bf16_t* __restrict__ wprojt)
{
    const int bx = blockIdx.x;
    if (bx < 2048) {
        int i = (bx * 256 + threadIdx.x) * 8;
        float4 a = *(const float4*)(x + i);
        float4 b = *(const float4*)(x + i + 4);
        bf16x8 v;
        v[0]=(bf16_t)a.x; v[1]=(bf16_t)a.y; v[2]=(bf16_t)a.z; v[3]=(bf16_t)a.w;
        v[4]=(bf16_t)b.x; v[5]=(bf16_t)b.y; v[6]=(bf16_t)b.z; v[7]=(bf16_t)b.w;
        *reinterpret_cast<bf16x8*>(xb + i) = v;
        return;
    }
    __shared__ float tile[32][33];
    const float* src; bf16_t* dst; int C, bxl, byl;
    if (bx < 5120) {
        int t = bx - 2048;
        byl = t / 96; bxl = t - byl * 96;   // 96 not pow2 -> real division
        src = Wqkv;  dst = wqkvt;  C = NQKV;
    } else {
        int t = bx - 5120;
        byl = t >> 5; bxl = t & 31;
        src = Wproj; dst = wprojt; C = DD;
    }
    const int R = DD;
    const int tx = threadIdx.x & 31, ty = threadIdx.x >> 5;
    const int r0 = byl * 32, c0 = bxl * 32;
    #pragma unroll
    for (int i = 0; i < 32; i += 8)
        tile[ty + i][tx] = src[(size_t)(r0 + ty + i) * C + c0 + tx];
    __syncthreads();
    #pragma unroll
    for (int i = 0; i < 32; i += 8)
        dst[(size_t)(c0 + ty + i) * R + r0 + tx] = (bf16_t)tile[tx][ty + i];
}

// ---------------------------------------------------------------------------
// QKV GEMM (unchanged from R7, verified): BM=128, BN=128, BK=32, 8 waves,
// 768 blocks = 3/CU, XCD-partitioned, counted-vmcnt 3-buffer pipeline.
// ---------------------------------------------------------------------------
__global__ __launch_bounds__(512, 6) void gemm_qkv(
    const bf16_t* __restrict__ A, const bf16_t* __restrict__ Bt,
    const float* __restrict__ bias,
    bf16_t* __restrict__ qw, bf16_t* __restrict__ kw, bf16_t* __restrict__ vtw)
{
    constexpr int K  = DD;          // 1024
    constexpr int BM = 128, BN = 128, BK = 32;
    constexpr int NT = K / BK;      // 32

    __shared__ __align__(16) bf16_t smem[24576];   // 49152 B -> 3 blocks/CU
    bf16_t* const Ab[3] = { smem,         smem + 4096,  smem + 8192 };
    bf16_t* const Bb[3] = { smem + 12288, smem + 16384, smem + 20480 };

    const int tid  = threadIdx.x;
    const int w    = tid >> 6;
    const int lane = tid & 63;
    const int lr   = lane & 15;
    const int quad = lane >> 4;
    const int wm   = w >> 2;        // 0..1 -> rows wm*64..+63
    const int wn   = w & 3;         // 0..3 -> cols wn*32..+31

    // XCD partition: xcd = flat&7; within XCD an 8(m) x 12(n) sub-grid.
    const int flat = blockIdx.y * 24 + blockIdx.x;
    const int xcd  = flat & 7;
    const int idx  = flat >> 3;            // 0..95
    const int m0   = ((xcd >> 1) * 8 + (idx & 7)) * BM;
    const int n0   = ((xcd & 1) * 12 + (idx >> 3)) * BN;

    f32x4 acc[4][2];
    #pragma unroll
    for (int mi = 0; mi < 4; mi++)
        #pragma unroll
        for (int ni = 0; ni < 2; ni++)
            acc[mi][ni] = (f32x4){0.f, 0.f, 0.f, 0.f};

    const bf16_t* aG = A  + (size_t)(m0 + (tid >> 2)) * K + (tid & 3) * 8;
    const bf16_t* bG = Bt + (size_t)(n0 + (tid >> 2)) * K + (tid & 3) * 8;

    auto stage = [&](int kt, bf16_t* Ad, bf16_t* Bd) {
        const int ko = kt * BK;
        gl_lds16(aG + ko, Ad + tid * 8);
        gl_lds16(bG + ko, Bd + tid * 8);
    };

    stage(0, Ab[0], Bb[0]);
    stage(1, Ab[1], Bb[1]);
    asm volatile("s_waitcnt vmcnt(2)" ::: "memory");
    __builtin_amdgcn_s_barrier();
    __builtin_amdgcn_sched_barrier(0);

    const int aOff = (wm * 64 + lr) * BK + quad * 8;
    const int bOff = (wn * 32 + lr) * BK + quad * 8;

    auto tileStep = [&](int t, const bf16_t* Ac, const bf16_t* Bc,
                        bf16_t* An, bf16_t* Bn) {
        bf16x8 af[4], bk[2];
        #pragma unroll
        for (int mi = 0; mi < 4; mi++)
            af[mi] = *(const bf16x8*)(Ac + aOff + mi * 16 * BK);
        #pragma unroll
        for (int ni = 0; ni < 2; ni++)
            bk[ni] = *(const bf16x8*)(Bc + bOff + ni * 16 * BK);
        if (t < NT - 2) stage(t + 2, An, Bn);
        __builtin_amdgcn_sched_barrier(0);
        __builtin_amdgcn_s_setprio(1);
        #pragma unroll
        for (int mi = 0; mi < 4; mi++)
            #pragma unroll
            for (int ni = 0; ni < 2; ni++)
                acc[mi][ni] = MF(af[mi], bk[ni], acc[mi][ni]);
        __builtin_amdgcn_s_setprio(0);
        __builtin_amdgcn_sched_barrier(0);
        if (t < NT - 2)       asm volatile("s_waitcnt vmcnt(2)" ::: "memory");
        else if (t == NT - 2) asm volatile("s_waitcnt vmcnt(0)" ::: "memory");
        __builtin_amdgcn_s_barrier();
        __builtin_amdgcn_sched_barrier(0);
    };

    #pragma unroll 1
    for (int tt = 0; tt < NT - 2; tt += 3) {
        tileStep(tt,     Ab[0], Bb[0], Ab[2], Bb[2]);
        tileStep(tt + 1, Ab[1], Bb[1], Ab[0], Bb[0]);
        tileStep(tt + 2, Ab[2], Bb[2], Ab[1], Bb[1]);
    }
    tileStep(NT - 2, Ab[0], Bb[0], nullptr, nullptr);   // t=30: vmcnt(0)
    tileStep(NT - 1, Ab[1], Bb[1], nullptr, nullptr);   // t=31

    // ---- epilogue (block-uniform q/k/v branch: BN=128 divides the 1024s) --
    const int which = n0 >> 10;           // 0=q, 1=k, 2=v
    const int dbase = n0 & 1023;
    const int b     = m0 >> 11;
    const int s0    = m0 & 2047;

    if (which < 2) {
        bf16_t* dst = (which == 0) ? qw : kw;
        const float scale = (which == 0) ? QPRESCALE : 1.0f;
        #pragma unroll
        for (int mi = 0; mi < 4; mi++) {
            const int rl0 = wm * 64 + mi * 16 + quad * 4;
            #pragma unroll
            for (int ni = 0; ni < 2; ni++) {
                const int col = n0 + wn * 32 + ni * 16 + lr;
                const float bcol = bias[col];
                const int d = col & 1023;
                const int h = d >> 6, hd = d & 63;
                #pragma unroll
                for (int reg = 0; reg < 4; reg++) {
                    const int s = s0 + rl0 + reg;
                    dst[(((size_t)(b * HH + h)) * SS + s) * HDD + hd] =
                        (bf16_t)((acc[mi][ni][reg] + bcol) * scale);
                }
            }
        }
    } else {
        // all-V block: transpose through LDS, then 16B stores along S
        __builtin_amdgcn_s_barrier();   // LDS reads of last tile done
        #pragma unroll
        for (int mi = 0; mi < 4; mi++) {
            const int rl0 = wm * 64 + mi * 16 + quad * 4;
            #pragma unroll
            for (int ni = 0; ni < 2; ni++) {
                const int lc = wn * 32 + ni * 16 + lr;
                const float bcol = bias[n0 + lc];
                bf16x4 pk;
                #pragma unroll
                for (int reg = 0; reg < 4; reg++)
                    pk[reg] = (bf16_t)(acc[mi][ni][reg] + bcol);
                *reinterpret_cast<bf16x4*>(&smem[lc * 132 + rl0]) = pk;
            }
        }
        __builtin_amdgcn_s_barrier();
        const int lcb = tid >> 4;            // 0..31
        const int rl  = (tid & 15) * 8;      // 0..120
        const int s   = s0 + rl;
        #pragma unroll
        for (int j = 0; j < 4; j++) {
            const int lc = j * 32 + lcb;
            bf16x8 vv = *reinterpret_cast<const bf16x8*>(&smem[lc * 132 + rl]);
            const int d = dbase + lc;
            const int h = d >> 6, hd = d & 63;
            *reinterpret_cast<bf16x8*>(
                vtw + (((size_t)(b * HH + h)) * HDD + hd) * SS + s) = vv;
        }
    }
}

// ---------------------------------------------------------------------------
// Proj GEMM (unchanged from R6/R7): BM=128, BN=128, BK=32, 8 waves,
// 256 blocks, counted-vmcnt 3-buffer pipeline.
// ---------------------------------------------------------------------------
__global__ __launch_bounds__(512, 6) void gemm_proj(
    const bf16_t* __restrict__ A, const bf16_t* __restrict__ Bt,
    const float* __restrict__ bias, float* __restrict__ outf)
{
    constexpr int K  = DD;          // 1024
    constexpr int N  = DD;
    constexpr int BM = 128, BN = 128, BK = 32;
    constexpr int NT = K / BK;      // 32

    __shared__ __align__(16) bf16_t smem[24576];   // 49152 B -> 3 blocks/CU
    bf16_t* const Ab[3] = { smem, smem + 4096, smem + 8192 };
    bf16_t* const Bb[3] = { smem + 12288, smem + 16384, smem + 20480 };

    const int tid  = threadIdx.x;
    const int w    = tid >> 6;
    const int lane = tid & 63;
    const int lr   = lane & 15;
    const int quad = lane >> 4;
    const int wm   = w >> 2;        // 0..1 -> rows wm*64..+63
    const int wn   = w & 3;         // 0..3 -> cols wn*32..+31

    const int flat = blockIdx.y * 8 + blockIdx.x;
    const int swz  = (flat & 7) * 32 + (flat >> 3);
    const int m0   = (swz >> 3) * BM;
    const int n0   = (swz & 7) * BN;

    f32x4 acc[4][2];
    #pragma unroll
    for (int mi = 0; mi < 4; mi++)
        #pragma unroll
        for (int ni = 0; ni < 2; ni++)
            acc[mi][ni] = (f32x4){0.f, 0.f, 0.f, 0.f};

    const bf16_t* aG = A  + (size_t)(m0 + (tid >> 2)) * K + (tid & 3) * 8;
    const bf16_t* bG = Bt + (size_t)(n0 + (tid >> 2)) * K + (tid & 3) * 8;

    auto stage = [&](int kt, bf16_t* Ad, bf16_t* Bd) {
        const int ko = kt * BK;
        gl_lds16(aG + ko, Ad + tid * 8);
        gl_lds16(bG + ko, Bd + tid * 8);
    };

    stage(0, Ab[0], Bb[0]);
    stage(1, Ab[1], Bb[1]);
    asm volatile("s_waitcnt vmcnt(2)" ::: "memory");
    __builtin_amdgcn_s_barrier();
    __builtin_amdgcn_sched_barrier(0);

    const int aOff = (wm * 64 + lr) * BK + quad * 8;
    const int bOff = (wn * 32 + lr) * BK + quad * 8;

    auto tileStep = [&](int t, const bf16_t* Ac, const bf16_t* Bc,
                        bf16_t* An, bf16_t* Bn) {
        bf16x8 af[4], bk[2];
        #pragma unroll
        for (int mi = 0; mi < 4; mi++)
            af[mi] = *(const bf16x8*)(Ac + aOff + mi * 16 * BK);
        #pragma unroll
        for (int ni = 0; ni < 2; ni++)
            bk[ni] = *(const bf16x8*)(Bc + bOff + ni * 16 * BK);
        if (t < NT - 2) stage(t + 2, An, Bn);
        __builtin_amdgcn_sched_barrier(0);
        __builtin_amdgcn_s_setprio(1);
        #pragma unroll
        for (int mi = 0; mi < 4; mi++)
            #pragma unroll
            for (int ni = 0; ni < 2; ni++)
                acc[mi][ni] = MF(af[mi], bk[ni], acc[mi][ni]);
        __builtin_amdgcn_s_setprio(0);
        __builtin_amdgcn_sched_barrier(0);
        if (t < NT - 2)       asm volatile("s_waitcnt vmcnt(2)" ::: "memory");
        else if (t == NT - 2) asm volatile("s_waitcnt vmcnt(0)" ::: "memory");
        __builtin_amdgcn_s_barrier();
        __builtin_amdgcn_sched_barrier(0);
    };

    #pragma unroll 1
    for (int tt = 0; tt < NT - 2; tt += 3) {
        tileStep(tt,     Ab[0], Bb[0], Ab[2], Bb[2]);
        tileStep(tt + 1, Ab[1], Bb[1], Ab[0], Bb[0]);
        tileStep(tt + 2, Ab[2], Bb[2], Ab[1], Bb[1]);
    }
    tileStep(NT - 2, Ab[0], Bb[0], nullptr, nullptr);   // t=30: vmcnt(0)
    tileStep(NT - 1, Ab[1], Bb[1], nullptr, nullptr);   // t=31

    #pragma unroll
    for (int mi = 0; mi < 4; mi++)
        #pragma unroll
        for (int ni = 0; ni < 2; ni++) {
            const int col = n0 + wn * 32 + ni * 16 + lr;
            const float bcol = bias[col];
            #pragma unroll
            for (int reg = 0; reg < 4; reg++) {
                const int row = m0 + wm * 64 + mi * 16 + quad * 4 + reg;
                outf[(size_t)row * N + col] = acc[mi][ni][reg] + bcol;
            }
        }
}

// ---------------------------------------------------------------------------
// Flash attention v9c (R9): exact R7 structure (verified 43.5-45 us) with
// ONE minimal change: l accumulated into f32x4 partials (dependent-add
// chain 32 -> 8 per iter; +3 VGPRs, no restructure). R8's exp/PV interleave
// REVERTED: it forced sfr+p+ap+o all-live -> scratch spill (WRITE_SIZE
// 8.2 -> 32.8 MB, attn 45 -> 76 us).
// ---------------------------------------------------------------------------
__global__ __launch_bounds__(512, 4) void attn_kernel(
    const bf16_t* __restrict__ qws, const bf16_t* __restrict__ kws,
    const bf16_t* __restrict__ vtws, bf16_t* __restrict__ ob)
{
    __shared__ __align__(16) bf16_t smem[35072];   // 70144 B -> 2 blocks/CU
    bf16_t* Ks = smem;                 // 2 buf x 2 g x 520*8 = 16640 el
    bf16_t* Vs = smem + 16640;         // 2 buf x 2 g x 64*72 = 18432 el

    const int tid  = threadIdx.x;
    const int w    = tid >> 6;
    const int g    = w >> 2;
    const int wg   = w & 3;
    const int lane = tid & 63;
    const int ln31 = lane & 31;
    const int ln5  = lane >> 5;

    // XCD swizzle: all 16 q-blocks of a bh pinned to XCD bh&7.
    const int flat = blockIdx.y * 16 + blockIdx.x;
    const int t2 = flat >> 3;
    const int bh = (t2 >> 4) * 8 + (flat & 7);
    const int qb = t2 & 15;
    const int b  = bh >> 4;
    const int h  = bh & 15;

    const bf16_t* Qh  = qws  + (size_t)bh * SS * HDD;
    const bf16_t* Kh  = kws  + (size_t)bh * SS * HDD;
    const bf16_t* Vth = vtws + (size_t)bh * HDD * SS;

    const int q0w    = qb * 128 + wg * 32;
    const int kvbase = g * 1024;

    bf16x8 aq[4];
    #pragma unroll
    for (int f = 0; f < 4; f++)
        aq[f] = *(const bf16x8*)(Qh + (size_t)(q0w + ln31) * HDD + f * 16 + ln5 * 8);

    const int gtid = tid & 255;
    const int sc = gtid & 7;
    const int sr = gtid >> 3;
    const int vcol = (sc >> 1) * 16 + (sc & 1) * 4;

    {
        const int ko = g * 520;
        const int vo = g * 4608;
        bf16x8 k0 = *(const bf16x8*)(Kh  + (size_t)(kvbase + sr     ) * HDD + sc * 8);
        bf16x8 k1 = *(const bf16x8*)(Kh  + (size_t)(kvbase + sr + 32) * HDD + sc * 8);
        bf16x8 v0 = *(const bf16x8*)(Vth + (size_t)(sr     ) * SS + kvbase + sc * 8);
        bf16x8 v1 = *(const bf16x8*)(Vth + (size_t)(sr + 32) * SS + kvbase + sc * 8);
        *reinterpret_cast<bf16x8*>(&Ks[(ko + sc * 65 + sr     ) * 8]) = k0;
        *reinterpret_cast<bf16x8*>(&Ks[(ko + sc * 65 + sr + 32) * 8]) = k1;
        bf16_t* vd0 = &Vs[vo + (sr     ) * 72 + vcol];
        bf16_t* vd1 = &Vs[vo + (sr + 32) * 72 + vcol];
        *reinterpret_cast<bf16x4*>(vd0)     = __builtin_shufflevector(v0, v0, 0,1,2,3);
        *reinterpret_cast<bf16x4*>(vd0 + 8) = __builtin_shufflevector(v0, v0, 4,5,6,7);
        *reinterpret_cast<bf16x4*>(vd1)     = __builtin_shufflevector(v1, v1, 0,1,2,3);
        *reinterpret_cast<bf16x4*>(vd1 + 8) = __builtin_shufflevector(v1, v1, 4,5,6,7);
    }
    __syncthreads();

    f32x4 lac = (f32x4){0.f, 0.f, 0.f, 0.f};
    f32x16 o[2];
    #pragma unroll
    for (int nh = 0; nh < 2; nh++)
        #pragma unroll
        for (int r = 0; r < 16; r++) o[nh][r] = 0.f;

    int buf = 0;
    for (int it = 0; it < 16; ++it) {
        const int ko = buf * 1040 + g * 520;
        const int vo = buf * 9216 + g * 4608;

        // K/V prefetch for it+1 issued FIRST (independent; long cover)
        bf16x8 nk0, nk1, nv0, nv1;
        const bool more = (it + 1 < 16);
        if (more) {
            const int kvn = kvbase + (it + 1) * 64;
            nk0 = *(const bf16x8*)(Kh  + (size_t)(kvn + sr     ) * HDD + sc * 8);
            nk1 = *(const bf16x8*)(Kh  + (size_t)(kvn + sr + 32) * HDD + sc * 8);
            nv0 = *(const bf16x8*)(Vth + (size_t)(sr     ) * SS + kvn + sc * 8);
            nv1 = *(const bf16x8*)(Vth + (size_t)(sr + 32) * SS + kvn + sc * 8);
        }

        f32x16 sfr[2];
        __builtin_amdgcn_s_setprio(1);
        #pragma unroll
        for (int ni = 0; ni < 2; ni++) {
            #pragma unroll
            for (int r = 0; r < 16; r++) sfr[ni][r] = 0.f;
            #pragma unroll
            for (int f = 0; f < 4; f++) {
                bf16x8 kb = *reinterpret_cast<const bf16x8*>(
                    &Ks[(ko + (2 * f + ln5) * 65 + ni * 32 + ln31) * 8]);
                sfr[ni] = __builtin_amdgcn_mfma_f32_32x32x16_bf16(kb, aq[f], sfr[ni], 0, 0, 0);
            }
        }
        __builtin_amdgcn_s_setprio(0);

        float p[2][16];
        #pragma unroll
        for (int ni = 0; ni < 2; ni++)
            #pragma unroll
            for (int r = 0; r < 16; r++) {
                p[ni][r] = __builtin_amdgcn_exp2f(sfr[ni][r]);
                lac[r & 3] += p[ni][r];
            }

        bf16x8 ap[4];
        #pragma unroll
        for (int c16 = 0; c16 < 4; c16++)
            #pragma unroll
            for (int j = 0; j < 8; j++)
                ap[c16][j] = (bf16_t)p[c16 >> 1][(c16 & 1) * 8 + j];

        __builtin_amdgcn_s_setprio(1);
        #pragma unroll
        for (int nh = 0; nh < 2; nh++) {
            const bf16_t* vrow = &Vs[vo + (nh * 32 + ln31) * 72];
            #pragma unroll
            for (int c16 = 0; c16 < 4; c16++) {
                bf16x8 vb = *reinterpret_cast<const bf16x8*>(vrow + c16 * 16 + 8 * ln5);
                o[nh] = __builtin_amdgcn_mfma_f32_32x32x16_bf16(ap[c16], vb, o[nh], 0, 0, 0);
            }
        }
        __builtin_amdgcn_s_setprio(0);

        if (more) {
            const int ko1 = (buf ^ 1) * 1040 + g * 520;
            const int vo1 = (buf ^ 1) * 9216 + g * 4608;
            *reinterpret_cast<bf16x8*>(&Ks[(ko1 + sc * 65 + sr     ) * 8]) = nk0;
            *reinterpret_cast<bf16x8*>(&Ks[(ko1 + sc * 65 + sr + 32) * 8]) = nk1;
            bf16_t* vd0 = &Vs[vo1 + (sr     ) * 72 + vcol];
            bf16_t* vd1 = &Vs[vo1 + (sr + 32) * 72 + vcol];
            *reinterpret_cast<bf16x4*>(vd0)     = __builtin_shufflevector(nv0, nv0, 0,1,2,3);
            *reinterpret_cast<bf16x4*>(vd0 + 8) = __builtin_shufflevector(nv0, nv0, 4,5,6,7);
            *reinterpret_cast<bf16x4*>(vd1)     = __builtin_shufflevector(nv1, nv1, 0,1,2,3);
            *reinterpret_cast<bf16x4*>(vd1 + 8) = __builtin_shufflevector(nv1, nv1, 4,5,6,7);
        }
        __syncthreads();
        buf ^= 1;
    }

    float l = (lac[0] + lac[1]) + (lac[2] + lac[3]);
    l += __shfl_xor(l, 32, 64);

    __syncthreads();
    float* Of = (float*)smem;
    float* Lf = (float*)(smem + 16384);
    if (ln5 == 0) Lf[g * 128 + wg * 32 + ln31] = l;
    if (g == 1) {
        #pragma unroll
        for (int nh = 0; nh < 2; nh++)
            #pragma unroll
            for (int r = 0; r < 16; r++) {
                const int q = (r & 3) + 8 * (r >> 2) + 4 * ln5;
                Of[(wg * 32 + q) * 64 + nh * 32 + ln31] = o[nh][r];
            }
    }
    __syncthreads();
    if (g == 0) {
        float inv[16];
        #pragma unroll
        for (int r = 0; r < 16; r++) {
            const int q = (r & 3) + 8 * (r >> 2) + 4 * ln5;
            inv[r] = 1.f / (Lf[wg * 32 + q] + Lf[128 + wg * 32 + q]);
        }
        #pragma unroll
        for (int nh = 0; nh < 2; nh++)
            #pragma unroll
            for (int r = 0; r < 16; r++) {
                const int q  = (r & 3) + 8 * (r >> 2) + 4 * ln5;
                const int hd = nh * 32 + ln31;
                float val = (o[nh][r] + Of[(wg * 32 + q) * 64 + hd]) * inv[r];
                ob[((size_t)b * SS + q0w + q) * DD + h * HDD + hd] = (bf16_t)val;
            }
    }
}

// ---------------------------------------------------------------------------
extern "C" void kernel_launch(void* const* d_in, const int* in_sizes, int n_in,
                              void* d_out, int out_size, void* d_ws, size_t ws_size,
                              hipStream_t stream) {
    const float* x     = (const float*)d_in[0];
    const float* Wqkv  = (const float*)d_in[1];
    const float* bqkv  = (const float*)d_in[2];
    const float* Wproj = (const float*)d_in[3];
    const float* bproj = (const float*)d_in[4];
    float* out = (float*)d_out;

    const size_t NEL = (size_t)MM * DD;   // 4194304
    bf16_t* qws    = (bf16_t*)d_ws;
    bf16_t* kws    = qws  + NEL;
    bf16_t* vtws   = kws  + NEL;
    bf16_t* xb     = vtws + NEL;          // aliased: xb then ows
    bf16_t* ows    = xb;
    bf16_t* wqkvt  = xb + NEL;
    bf16_t* wprojt = wqkvt + (size_t)NQKV * DD;

    prep<<<6144, 256, 0, stream>>>(x, Wqkv, Wproj, xb, wqkvt, wprojt);

    gemm_qkv<<<dim3(NQKV / 128, MM / 128), 512, 0, stream>>>(
        xb, wqkvt, bqkv, qws, kws, vtws);

    attn_kernel<<<dim3(SS / 128, BB * HH), 512, 0, stream>>>(qws, kws, vtws, ows);

    gemm_proj<<<dim3(DD / 128, MM / 128), 512, 0, stream>>>(
        ows, wprojt, bproj, out);
}